// Round 14
// baseline (98.031 us; speedup 1.0000x reference)
//
#include <hip/hip_runtime.h>

#define HH    1024
#define WW    1024
#define KS    15
#define PAD   7
#define CELL  256
#define WX    16            // x-width per WAVE (one 64-thread block = one wave)
#define STRIP 128           // output rows per wave
#define TROWS (STRIP + 2*PAD)   // 142
#define TCOLS 32            // staged halves per row (64B rows, bank-even)
#define NJP   (STRIP / 16)  // 8 row-patches
#define NGRP  (TROWS * 8)   // 1136 float4 groups (8 per row)
#define NFULL 17            // 17*64 = 1088 full rounds, tail 48
#define AWS_CELL_BYTES (KS * 1024)   // 15 fragments x 1KB

typedef _Float16     f16x8 __attribute__((ext_vector_type(8)));
typedef _Float16     f16x4 __attribute__((ext_vector_type(4)));
typedef float        f32x4 __attribute__((ext_vector_type(4)));
typedef unsigned int u32x4 __attribute__((ext_vector_type(4)));

// ---- prep: materialize normalized Toeplitz A fragments per cell into d_ws ----
// Layout: u32 word  cell*3840 + dy*256 + (i*16 + k2); main lane (g,cc) loads
// words cc*16+4g..+3 at +dy*256: one coalesced dwordx4 per fragment.
__global__ __launch_bounds__(256) void pb_prep_kernel(
    const float* __restrict__ kern, unsigned int* __restrict__ aws)
{
    const int cell = blockIdx.x;           // cj*4+ci
    const int tid  = threadIdx.x;
    const int lane = tid & 63;
    const float* kp = kern + cell * (KS * KS);

    float s = 0.f;
    #pragma unroll
    for (int i = 0; i < 4; ++i) {
        int t = lane + 64 * i;
        s += (t < KS * KS) ? kp[t] : 0.f;
    }
    #pragma unroll
    for (int m = 1; m < 64; m <<= 1) s += __shfl_xor(s, m, 64);
    const float inv = 1.0f / (s + 1e-12f);

    const int i  = tid >> 4;               // x-position (A row)
    const int k2 = tid & 15;               // half-pair index
    unsigned int* wp = aws + cell * (AWS_CELL_BYTES / 4) + tid;

    for (int dy = 0; dy < KS; ++dy) {
        float v0 = 0.f, v1 = 0.f;
        int dx0 = 2 * k2 - i - 1;          // A[i][k] = kh[k-i-1]
        int dx1 = dx0 + 1;
        if (dx0 >= 0 && dx0 < KS) v0 = kp[dy * KS + dx0] * inv;
        if (dx1 >= 0 && dx1 < KS) v1 = kp[dy * KS + dx1] * inv;
        f16x4 h; h[0] = (_Float16)v0; h[1] = (_Float16)v1; h[2] = 0; h[3] = 0;
        unsigned long long u = __builtin_bit_cast(unsigned long long, h);
        wp[dy * 256] = (unsigned int)u;
    }
}

// ---- main: ZERO-BARRIER design. One wave per block; private 142x32 f16 tile.
// R11-R13 plateaued at ~58 us with all pipes <43%: 8 block-wide barriers per
// block kept the ~16 resident waves in lockstep, starving the LDS pipe around
// every rendezvous. Here each wave stages its own halo strip (2.2x staging
// amplification, L2/L3-absorbed) and never synchronizes with anyone.
// Registers: af[15] = 60 AGPR + ~55 VGPR < 128 cap -> 4 waves/SIMD; LDS
// 16 x 9.1 KB = 145 KB/CU fits.
__global__ __launch_bounds__(64, 4) void pb_mfma_kernel(
    const float* __restrict__ x,
    const unsigned int* __restrict__ aws,
    float* __restrict__ out)
{
    __shared__ __align__(16) _Float16 s_tile[TROWS * TCOLS];   // 9088 B

    const int lane = threadIdx.x;        // block == one wave
    const int g    = lane >> 4;          // k-group 0..3
    const int cc   = lane & 15;          // A-row / B-col index

    const int x0    = blockIdx.x * WX;   // 64 x-strips of 16
    const int ci    = blockIdx.x >> 4;   // cell col (16 strips per cell)
    const int strip = blockIdx.y & 1;
    const int cj    = blockIdx.y >> 1;   // cell row
    const int bc    = blockIdx.z;        // plane (b*c)

    const int cellx0 = ci * CELL;
    const int celly0 = cj * CELL, celly1 = celly0 + CELL - 1;
    const int sy0    = celly0 + strip * STRIP;

    const float* plane = x + (size_t)bc * HH * WW;

    // ---- A fragments: 15 coalesced dwordx4 loads, pinned resident (R8) ----
    const u32x4* ap = (const u32x4*)(aws + (cj * 4 + ci) * (AWS_CELL_BYTES / 4))
                      + cc * 4 + g;
    u32x4 af[KS];
    #pragma unroll
    for (int dy = 0; dy < KS; ++dy) af[dy] = ap[dy * 64];
    #pragma unroll
    for (int dy = 0; dy < KS; ++dy) asm volatile("" : "+v"(af[dy]));

    // ---- stage private 142x32 tile; window x = [x0-8, x0+23] (16B-aligned) ----
    // group idx: row = idx>>3, c4 = idx&7 (8 float4 groups per row).
    auto stage_group = [&](int idx) {
        int row  = idx >> 3;
        int c4   = idx & 7;
        int gy   = min(max(sy0 - PAD + row, celly0), celly1);
        int gx0  = x0 - 8 + 4 * c4;
        int gx0c = min(max(gx0, cellx0), cellx0 + CELL - 4);
        float4 v = *(const float4*)(plane + (size_t)gy * WW + gx0c);
        bool lo = gx0 <  cellx0;
        bool hi = gx0 >  cellx0 + CELL - 4;
        float e0 = hi ? v.w : v.x;
        float e1 = lo ? v.x : (hi ? v.w : v.y);
        float e2 = lo ? v.x : (hi ? v.w : v.z);
        float e3 = lo ? v.x : v.w;
        f16x4 h;
        h[0] = (_Float16)e0; h[1] = (_Float16)e1;
        h[2] = (_Float16)e2; h[3] = (_Float16)e3;
        *(f16x4*)(s_tile + row * TCOLS + 4 * c4) = h;   // ds_write_b64
    };
    #pragma unroll
    for (int i = 0; i < NFULL; ++i) stage_group(lane + 64 * i);
    if (lane < NGRP - 64 * NFULL) stage_group(64 * NFULL + lane);

    // no barrier: intra-wave ds_write -> ds_read ordering via lgkmcnt interlock

    // ---- compute: 8 patches x 15 dy ----
    const _Float16* bbase = s_tile + cc * TCOLS + g * 8;
    float* oplane = out + (size_t)bc * HH * WW;

    #pragma unroll
    for (int jp = 0; jp < NJP; ++jp) {
        f32x4 acc0 = {0.f, 0.f, 0.f, 0.f};
        f32x4 acc1 = {0.f, 0.f, 0.f, 0.f};
        #pragma unroll
        for (int dy = 0; dy < KS; ++dy) {
            f16x8 b = *(const f16x8*)(bbase + (16 * jp + dy) * TCOLS);
            if (dy & 1)
                acc1 = __builtin_amdgcn_mfma_f32_16x16x32_f16(
                           __builtin_bit_cast(f16x8, af[dy]), b, acc1, 0, 0, 0);
            else
                acc0 = __builtin_amdgcn_mfma_f32_16x16x32_f16(
                           __builtin_bit_cast(f16x8, af[dy]), b, acc0, 0, 0, 0);
        }
        f32x4 r = acc0 + acc1;
        // D: col=lane&15 (image row), row=4*(lane>>4)+e (x position)
        float* op = oplane + (size_t)(sy0 + 16 * jp + cc) * WW + x0 + 4 * g;
        *(f32x4*)op = r;
    }
}

extern "C" void kernel_launch(void* const* d_in, const int* in_sizes, int n_in,
                              void* d_out, int out_size, void* d_ws, size_t ws_size,
                              hipStream_t stream) {
    (void)in_sizes; (void)n_in; (void)ws_size; (void)out_size;
    const float* x    = (const float*)d_in[0];
    const float* kern = (const float*)d_in[1];
    float* out        = (float*)d_out;
    unsigned int* aws = (unsigned int*)d_ws;   // 16 cells x 15 KiB = 240 KiB

    pb_prep_kernel<<<16, 256, 0, stream>>>(kern, aws);
    dim3 grid(WW / WX, 8, 8 * 3);   // 64 x-strips, 8 y-strips, 24 planes
    pb_mfma_kernel<<<grid, 64, 0, stream>>>(x, aws, out);
}

// Round 15
// 56.002 us; speedup vs baseline: 1.7505x; 1.7505x over previous
//
#include <hip/hip_runtime.h>

#define HH    1024
#define WW    1024
#define KS    15
#define PAD   7
#define CELL  256
#define BX    64            // x-width per block (4 waves x 16)
#define TROWS 142           // tile rows (128-row strip + 2*PAD)
#define TCOLS 80            // staged halves per row (160B rows)
#define NITER 16            // 2 strips x 8 patches
#define CHN   18            // 2 strips x 9 chunks (8 full + 14-row tail each)
#define AWS_CELL_BYTES (KS * 1024)   // 15 fragments x 1KB

typedef _Float16     f16x8 __attribute__((ext_vector_type(8)));
typedef _Float16     f16x4 __attribute__((ext_vector_type(4)));
typedef float        f32x4 __attribute__((ext_vector_type(4)));
typedef unsigned int u32x4 __attribute__((ext_vector_type(4)));

// Barrier with LDS ordering only (no vmcnt(0) drain): output stores and
// prefetch loads ride across; ds_write data dependency gives precise vmcnt.
static __device__ __forceinline__ void light_barrier() {
    asm volatile("s_waitcnt lgkmcnt(0)\n\ts_barrier" ::: "memory");
}

// ---- prep: materialize normalized Toeplitz A fragments per cell into d_ws ----
__global__ __launch_bounds__(256) void pb_prep_kernel(
    const float* __restrict__ kern, unsigned int* __restrict__ aws)
{
    const int cell = blockIdx.x;           // cj*4+ci
    const int tid  = threadIdx.x;
    const int lane = tid & 63;
    const float* kp = kern + cell * (KS * KS);

    float s = 0.f;
    #pragma unroll
    for (int i = 0; i < 4; ++i) {
        int t = lane + 64 * i;
        s += (t < KS * KS) ? kp[t] : 0.f;
    }
    #pragma unroll
    for (int m = 1; m < 64; m <<= 1) s += __shfl_xor(s, m, 64);
    const float inv = 1.0f / (s + 1e-12f);

    const int i  = tid >> 4;               // x-position (A row)
    const int k2 = tid & 15;               // half-pair index
    unsigned int* wp = aws + cell * (AWS_CELL_BYTES / 4) + tid;

    for (int dy = 0; dy < KS; ++dy) {
        float v0 = 0.f, v1 = 0.f;
        int dx0 = 2 * k2 - i - 1;          // A[i][k] = kh[k-i-1]
        int dx1 = dx0 + 1;
        if (dx0 >= 0 && dx0 < KS) v0 = kp[dy * KS + dx0] * inv;
        if (dx1 >= 0 && dx1 < KS) v1 = kp[dy * KS + dx1] * inv;
        f16x4 h; h[0] = (_Float16)v0; h[1] = (_Float16)v1; h[2] = 0; h[3] = 0;
        unsigned long long u = __builtin_bit_cast(unsigned long long, h);
        wp[dy * 256] = (unsigned int)u;
    }
}

// ---- main: one block = one 256-row cell-column; 16-iteration rolling pipe.
// R13 paid {af load + pipeline fill/drain} per 128 rows; here once per 256.
// Chunk g (global 0..17): strip = g/9, lc = g%9, tile rows 16lc..16lc+15
// (lc=8: 14 rows). Strip-1 chunks land in tile rows already dead to strip-0
// patches (verified per-iter), so one linear 142-row tile serves both strips
// with compile-time LDS offsets. Schedule: prologue stages ch0-2, issues
// ch3-4; iter t: issue ch(t+5), compute patch(t), write ch(t+3), barrier.
// Each staged chunk has 2 full iterations of latency cover.
__global__ __launch_bounds__(256, 4) void pb_mfma_kernel(
    const float* __restrict__ x,
    const unsigned int* __restrict__ aws,
    float* __restrict__ out)
{
    __shared__ __align__(16) _Float16 s_tile[TROWS * TCOLS];   // 22720 B

    const int tid  = threadIdx.x;
    const int lane = tid & 63;
    const int w    = tid >> 6;           // wave id: x sub-block
    const int g    = lane >> 4;          // k-group 0..3
    const int cc   = lane & 15;          // A-row / B-col index

    const int bx0 = blockIdx.x * BX;
    const int ci  = blockIdx.x >> 2;     // cell col
    const int cj  = blockIdx.y;          // cell row
    const int bc  = blockIdx.z;          // plane (b*c)

    const int cellx0 = ci * CELL;
    const int celly0 = cj * CELL, celly1 = celly0 + CELL - 1;

    const float* plane = x + (size_t)bc * HH * WW;

    // ---- A fragments: 15 coalesced dwordx4 loads, pinned resident (R8) ----
    const u32x4* ap = (const u32x4*)(aws + (cj * 4 + ci) * (AWS_CELL_BYTES / 4))
                      + cc * 4 + g;
    u32x4 af[KS];
    #pragma unroll
    for (int dy = 0; dy < KS; ++dy) af[dy] = ap[dy * 64];
    #pragma unroll
    for (int dy = 0; dy < KS; ++dy) asm volatile("" : "+v"(af[dy]));

    // ---- staging helpers ----
    // chunk meta: strip = gch/9, lc = gch%9; slot s in {0,1}: idx = s*256+tid.
    // ng = 320 (lc<8) or 280 (lc==8); slot0 always valid (ng >= 280 > 255).
    auto stage_addr = [&](int strip, int lc, int idx) -> const float* {
        int r20  = idx / 20;
        int c4   = idx - r20 * 20;
        int row  = lc * 16 + r20;                       // tile row 0..141
        int gy   = min(max(celly0 + strip * 128 - PAD + row, celly0), celly1);
        int gx0  = bx0 - 8 + 4 * c4;
        int gx0c = min(max(gx0, cellx0), cellx0 + CELL - 4);
        return plane + (size_t)gy * WW + gx0c;
    };
    auto write_group = [&](int lc, int idx, float4 v) {
        int r20 = idx / 20;
        int c4  = idx - r20 * 20;
        int row = lc * 16 + r20;
        int gx0 = bx0 - 8 + 4 * c4;
        bool lo = gx0 <  cellx0;
        bool hi = gx0 >  cellx0 + CELL - 4;
        float e0 = hi ? v.w : v.x;
        float e1 = lo ? v.x : (hi ? v.w : v.y);
        float e2 = lo ? v.x : (hi ? v.w : v.z);
        float e3 = lo ? v.x : v.w;
        f16x4 h;
        h[0] = (_Float16)e0; h[1] = (_Float16)e1;
        h[2] = (_Float16)e2; h[3] = (_Float16)e3;
        *(f16x4*)(s_tile + row * TCOLS + 4 * c4) = h;   // ds_write_b64
    };
    auto issue_chunk = [&](int gch, float4& v0, float4& v1, bool& h1) {
        int strip = gch >= 9;
        int lc    = gch - 9 * strip;
        int ng    = (lc == 8) ? 280 : 320;
        v0 = *(const float4*)stage_addr(strip, lc, tid);
        h1 = 256 + tid < ng;
        if (h1) v1 = *(const float4*)stage_addr(strip, lc, 256 + tid);
    };
    auto write_chunk = [&](int gch, float4 v0, float4 v1, bool h1) {
        int strip = gch >= 9;
        int lc    = gch - 9 * strip;
        (void)strip;
        write_group(lc, tid, v0);
        if (h1) write_group(lc, 256 + tid, v1);
    };

    // ---- prologue: stage chunks 0..2; issue 3,4 as 2-deep pending ----
    {
        float4 a0, a1, b0, b1, c0, c1; bool ha1, hb1, hc1;
        issue_chunk(0, a0, a1, ha1);
        issue_chunk(1, b0, b1, hb1);
        issue_chunk(2, c0, c1, hc1);
        write_chunk(0, a0, a1, ha1);
        write_chunk(1, b0, b1, hb1);
        write_chunk(2, c0, c1, hc1);
    }
    float4 pA0, pA1, pB0, pB1; bool hA1, hB1;
    issue_chunk(3, pA0, pA1, hA1);
    issue_chunk(4, pB0, pB1, hB1);
    light_barrier();

    // ---- rolling main loop: 16 iterations (2 strips x 8 patches) ----
    const _Float16* bbase = s_tile + cc * TCOLS + w * 16 + g * 8;
    float* oplane = out + (size_t)bc * HH * WW;

    #pragma unroll
    for (int t = 0; t < NITER; ++t) {
        const int strip = t >> 3;
        const int jpl   = t & 7;

        // issue chunk t+5 (written at iter t+2: two iterations of cover)
        float4 n0 = {0,0,0,0}, n1 = {0,0,0,0}; bool hn1 = false;
        if (t + 5 < CHN) issue_chunk(t + 5, n0, n1, hn1);

        // compute patch: reads tile rows 16*jpl .. 16*jpl+30
        f32x4 acc0 = {0.f, 0.f, 0.f, 0.f};
        f32x4 acc1 = {0.f, 0.f, 0.f, 0.f};
        #pragma unroll
        for (int dy = 0; dy < KS; ++dy) {
            f16x8 b = *(const f16x8*)(bbase + (16 * jpl + dy) * TCOLS);
            if (dy & 1)
                acc1 = __builtin_amdgcn_mfma_f32_16x16x32_f16(
                           __builtin_bit_cast(f16x8, af[dy]), b, acc1, 0, 0, 0);
            else
                acc0 = __builtin_amdgcn_mfma_f32_16x16x32_f16(
                           __builtin_bit_cast(f16x8, af[dy]), b, acc0, 0, 0, 0);
        }
        f32x4 r = acc0 + acc1;
        // D: col=lane&15 (image row), row=4*(lane>>4)+e (x position)
        float* op = oplane
                  + (size_t)(celly0 + strip * 128 + 16 * jpl + cc) * WW
                  + bx0 + 16 * w + 4 * g;
        *(f32x4*)op = r;   // rides across light barriers, no drain

        // land pending-oldest chunk t+3 (rows disjoint from patch t's reads)
        if (t + 3 < CHN) write_chunk(t + 3, pA0, pA1, hA1);
        light_barrier();

        // rotate pending
        pA0 = pB0; pA1 = pB1; hA1 = hB1;
        pB0 = n0;  pB1 = n1;  hB1 = hn1;
    }
}

extern "C" void kernel_launch(void* const* d_in, const int* in_sizes, int n_in,
                              void* d_out, int out_size, void* d_ws, size_t ws_size,
                              hipStream_t stream) {
    (void)in_sizes; (void)n_in; (void)ws_size; (void)out_size;
    const float* x    = (const float*)d_in[0];
    const float* kern = (const float*)d_in[1];
    float* out        = (float*)d_out;
    unsigned int* aws = (unsigned int*)d_ws;   // 16 cells x 15 KiB = 240 KiB

    pb_prep_kernel<<<16, 256, 0, stream>>>(kern, aws);
    dim3 grid(WW / BX, 4, 8 * 3);   // 16 x-strips, 4 cell-rows, 24 planes
    pb_mfma_kernel<<<grid, 256, 0, stream>>>(x, aws, out);
}